// Round 4
// baseline (409.196 us; speedup 1.0000x reference)
//
#include <hip/hip_runtime.h>
#include <math.h>

#define BB 32
#define DD 1024
#define SS 4096
#define VVOUT 32003
#define NCHUNK 32
#define ROWS_PER_CHUNK 128
#define PART_STRIDE 1032

__device__ __forceinline__ float sigmoidf_(float x) { return 1.f / (1.f + expf(-x)); }

// One wave per output dim d (1024 waves). Computes h[m][d] for all 32 m.
// gi = X @ Wih[:, :K].T + bih ; gh = bhh (h_prev = 0)
// r = sig(gi_r + bhh_r); z = sig(gi_z + bhh_z); n = tanh(gi_n + r*bhh_n); h = (1-z)*n
template <bool GATHER>
__global__ __launch_bounds__(256) void gru_fused(
    const float* __restrict__ Xbase,    // emb table (GATHER) or h (32x1024)
    const int* __restrict__ tokens,
    const float* __restrict__ Wih, int ldw,
    const float* __restrict__ bih, const float* __restrict__ bhh,
    float* __restrict__ hout) {
  int d = (blockIdx.x * 256 + threadIdx.x) >> 6;   // 0..1023
  int lane = threadIdx.x & 63;

  // prefetch all W: 3 gate rows x 4 chunks (chunk = 256 floats, float4/lane)
  float4 wr_[4], wz_[4], wn_[4];
  const float* w0 = Wih + (size_t)d * ldw + 4 * lane;
  const float* w1 = Wih + (size_t)(1024 + d) * ldw + 4 * lane;
  const float* w2 = Wih + (size_t)(2048 + d) * ldw + 4 * lane;
#pragma unroll
  for (int c = 0; c < 4; c++) {
    wr_[c] = *(const float4*)(w0 + 256 * c);
    wz_[c] = *(const float4*)(w1 + 256 * c);
    wn_[c] = *(const float4*)(w2 + 256 * c);
  }
  int tok = 0;
  if (GATHER) tok = tokens[lane & 31];

  float vr = 0.f, vz = 0.f, vn = 0.f;
  for (int m = 0; m < BB; m++) {
    const float* xm;
    if (GATHER) {
      int t = __shfl(tok, m, 64);
      xm = Xbase + (size_t)t * DD + 4 * lane;
    } else {
      xm = Xbase + (size_t)m * DD + 4 * lane;
    }
    float pr = 0.f, pz = 0.f, pn = 0.f;
#pragma unroll
    for (int c = 0; c < 4; c++) {
      float4 x4 = *(const float4*)(xm + 256 * c);
      pr += wr_[c].x * x4.x + wr_[c].y * x4.y + wr_[c].z * x4.z + wr_[c].w * x4.w;
      pz += wz_[c].x * x4.x + wz_[c].y * x4.y + wz_[c].z * x4.z + wz_[c].w * x4.w;
      pn += wn_[c].x * x4.x + wn_[c].y * x4.y + wn_[c].z * x4.z + wn_[c].w * x4.w;
    }
#pragma unroll
    for (int off = 32; off; off >>= 1) {
      pr += __shfl_xor(pr, off, 64);
      pz += __shfl_xor(pz, off, 64);
      pn += __shfl_xor(pn, off, 64);
    }
    if (lane == m) { vr = pr; vz = pz; vn = pn; }
  }
  if (lane < BB) {
    float r = sigmoidf_(vr + bih[d] + bhh[d]);
    float z = sigmoidf_(vz + bih[1024 + d] + bhh[1024 + d]);
    float n = tanhf(vn + bih[2048 + d] + r * bhh[2048 + d]);
    hout[(size_t)lane * DD + d] = (1.f - z) * n;
  }
}

// One enc pass: per (b, s-chunk) online-softmax partial {M, L, U[1024]}.
__global__ __launch_bounds__(256) void attn_partial(
    const float* __restrict__ ht, const float* __restrict__ enc,
    const int* __restrict__ mask, float* __restrict__ part) {
  int b = blockIdx.x;
  int chunk = blockIdx.y;
  int w = threadIdx.x >> 6;
  int l = threadIdx.x & 63;
  int s0 = chunk * ROWS_PER_CHUNK;

  __shared__ int smask[ROWS_PER_CHUNK];
  __shared__ float sml[4][2];
  __shared__ float sacc[4][1024];
  if (threadIdx.x < ROWS_PER_CHUNK)
    smask[threadIdx.x] = mask[(size_t)b * SS + s0 + threadIdx.x];

  const float* encb = enc + (size_t)b * SS * DD;
  const float* htb = ht + (size_t)b * DD;
  float4 h4[4];
#pragma unroll
  for (int j = 0; j < 4; j++) h4[j] = *(const float4*)(htb + 256 * j + 4 * l);
  __syncthreads();

  float4 acc[4];
#pragma unroll
  for (int j = 0; j < 4; j++) acc[j] = make_float4(0.f, 0.f, 0.f, 0.f);
  float mw = -INFINITY, lw = 0.f;

  int rbase = w * 32;
  for (int ii = 0; ii < 8; ii++) {
    int rr = rbase + 4 * ii;
    int mk0 = smask[rr], mk1 = smask[rr + 1], mk2 = smask[rr + 2], mk3 = smask[rr + 3];
    if ((mk0 | mk1 | mk2 | mk3) == 0) continue;
    const float* er = encb + (size_t)(s0 + rr) * DD + 4 * l;
    float4 e0[4], e1[4], e2[4], e3[4];
#pragma unroll
    for (int j = 0; j < 4; j++) {
      e0[j] = *(const float4*)(er + 256 * j);
      e1[j] = *(const float4*)(er + DD + 256 * j);
      e2[j] = *(const float4*)(er + 2 * DD + 256 * j);
      e3[j] = *(const float4*)(er + 3 * DD + 256 * j);
    }
    float p0 = 0.f, p1 = 0.f, p2 = 0.f, p3 = 0.f;
#pragma unroll
    for (int j = 0; j < 4; j++) {
      p0 += e0[j].x * h4[j].x + e0[j].y * h4[j].y + e0[j].z * h4[j].z + e0[j].w * h4[j].w;
      p1 += e1[j].x * h4[j].x + e1[j].y * h4[j].y + e1[j].z * h4[j].z + e1[j].w * h4[j].w;
      p2 += e2[j].x * h4[j].x + e2[j].y * h4[j].y + e2[j].z * h4[j].z + e2[j].w * h4[j].w;
      p3 += e3[j].x * h4[j].x + e3[j].y * h4[j].y + e3[j].z * h4[j].z + e3[j].w * h4[j].w;
    }
#pragma unroll
    for (int off = 32; off; off >>= 1) {
      p0 += __shfl_xor(p0, off, 64);
      p1 += __shfl_xor(p1, off, 64);
      p2 += __shfl_xor(p2, off, 64);
      p3 += __shfl_xor(p3, off, 64);
    }
    if (!mk0) p0 = -INFINITY;
    if (!mk1) p1 = -INFINITY;
    if (!mk2) p2 = -INFINITY;
    if (!mk3) p3 = -INFINITY;
    float mn = fmaxf(fmaxf(mw, fmaxf(p0, p1)), fmaxf(p2, p3));
    if (mn > -INFINITY) {
      float sc = (mw > -INFINITY) ? __expf(mw - mn) : 0.f;
      float a0 = __expf(p0 - mn);
      float a1 = __expf(p1 - mn);
      float a2 = __expf(p2 - mn);
      float a3 = __expf(p3 - mn);
      lw = lw * sc + (a0 + a1) + (a2 + a3);
#pragma unroll
      for (int j = 0; j < 4; j++) {
        acc[j].x = acc[j].x * sc + a0 * e0[j].x + a1 * e1[j].x + a2 * e2[j].x + a3 * e3[j].x;
        acc[j].y = acc[j].y * sc + a0 * e0[j].y + a1 * e1[j].y + a2 * e2[j].y + a3 * e3[j].y;
        acc[j].z = acc[j].z * sc + a0 * e0[j].z + a1 * e1[j].z + a2 * e2[j].z + a3 * e3[j].z;
        acc[j].w = acc[j].w * sc + a0 * e0[j].w + a1 * e1[j].w + a2 * e2[j].w + a3 * e3[j].w;
      }
      mw = mn;
    }
  }

  if (l == 0) { sml[w][0] = mw; sml[w][1] = lw; }
#pragma unroll
  for (int j = 0; j < 4; j++) *(float4*)&sacc[w][256 * j + 4 * l] = acc[j];
  __syncthreads();

  float M = fmaxf(fmaxf(sml[0][0], sml[1][0]), fmaxf(sml[2][0], sml[3][0]));
  float L = 0.f;
  float scw[4];
#pragma unroll
  for (int ww = 0; ww < 4; ww++) {
    float mm = sml[ww][0];
    float s_ = (mm == -INFINITY) ? 0.f : __expf(mm - M);
    scw[ww] = s_;
    L += sml[ww][1] * s_;
  }
  float* P = part + (size_t)(b * NCHUNK + chunk) * PART_STRIDE;
  int tid = threadIdx.x;
  if (tid == 0) { P[0] = M; P[1] = L; }
  float4 u = make_float4(0.f, 0.f, 0.f, 0.f);
#pragma unroll
  for (int ww = 0; ww < 4; ww++) {
    float4 a = *(const float4*)&sacc[ww][4 * tid];
    u.x += scw[ww] * a.x; u.y += scw[ww] * a.y;
    u.z += scw[ww] * a.z; u.w += scw[ww] * a.w;
  }
  *(float4*)&P[8 + 4 * tid] = u;
}

// Combine 32 partials per b -> summary; build xcat = [h_t | summary]
__global__ __launch_bounds__(256) void attn_reduce(
    const float* __restrict__ part, const float* __restrict__ ht,
    float* __restrict__ xcat) {
  int b = blockIdx.x;
  int tid = threadIdx.x;
  const float* Pb = part + (size_t)b * NCHUNK * PART_STRIDE;
  float M = -INFINITY;
#pragma unroll
  for (int c = 0; c < NCHUNK; c++) M = fmaxf(M, Pb[c * PART_STRIDE]);
  float L = 0.f;
  float sc[NCHUNK];
#pragma unroll
  for (int c = 0; c < NCHUNK; c++) {
    float mc = Pb[c * PART_STRIDE];
    float s_ = (mc == -INFINITY) ? 0.f : __expf(mc - M);
    sc[c] = s_;
    L += Pb[c * PART_STRIDE + 1] * s_;
  }
  float inv = (L > 0.f) ? 1.f / L : 0.f;
  float4 u = make_float4(0.f, 0.f, 0.f, 0.f);
#pragma unroll
  for (int c = 0; c < NCHUNK; c++) {
    float4 a = *(const float4*)&Pb[c * PART_STRIDE + 8 + 4 * tid];
    u.x += sc[c] * a.x; u.y += sc[c] * a.y;
    u.z += sc[c] * a.z; u.w += sc[c] * a.w;
  }
  u.x *= inv; u.y *= inv; u.z *= inv; u.w *= inv;
  *(float4*)&xcat[(size_t)b * 2048 + 1024 + 4 * tid] = u;
  *(float4*)&xcat[(size_t)b * 2048 + 4 * tid] = *(const float4*)&ht[(size_t)b * DD + 4 * tid];
}

// One wave per output n (1024 waves). opre[m][n] = bias[n] + xcat[m] . W[n]
__global__ __launch_bounds__(256) void preout_fused(
    const float* __restrict__ xcat, const float* __restrict__ W,
    const float* __restrict__ bias, float* __restrict__ Y) {
  int n = (blockIdx.x * 256 + threadIdx.x) >> 6;   // 0..1023
  int lane = threadIdx.x & 63;
  float4 wreg[8];
  const float* wr = W + (size_t)n * 2048 + 4 * lane;
#pragma unroll
  for (int c = 0; c < 8; c++) wreg[c] = *(const float4*)(wr + 256 * c);
  float vm = 0.f;
  for (int m = 0; m < BB; m++) {
    const float* xm = xcat + (size_t)m * 2048 + 4 * lane;
    float p = 0.f;
#pragma unroll
    for (int c = 0; c < 8; c++) {
      float4 x4 = *(const float4*)(xm + 256 * c);
      p += wreg[c].x * x4.x + wreg[c].y * x4.y + wreg[c].z * x4.z + wreg[c].w * x4.w;
    }
#pragma unroll
    for (int off = 32; off; off >>= 1) p += __shfl_xor(p, off, 64);
    if (lane == m) vm = p;
  }
  if (lane < BB) Y[(size_t)lane * DD + n] = vm + bias[n];
}

// logits: 16 rows/wave, 4 lanes/row, full K=1024, fused bias, no atomics.
__global__ __launch_bounds__(256) void logits_mm(
    const float* __restrict__ X, const float* __restrict__ W,
    const float* __restrict__ bias, float* __restrict__ Y) {
  int lane = threadIdx.x & 63;
  int w = threadIdx.x >> 6;
  int c = lane & 3;
  int r = blockIdx.x * 64 + w * 16 + (lane >> 2);
  bool valid = r < VVOUT;
  int rr = valid ? r : VVOUT - 1;
  const float* wrow = W + (size_t)rr * DD + 4 * c;
  const float* xp = X + 4 * c;
  float acc[BB];
#pragma unroll
  for (int m = 0; m < BB; m++) acc[m] = 0.f;
#pragma unroll 2
  for (int kk = 0; kk < DD; kk += 16) {
    float4 w4 = *(const float4*)(wrow + kk);
#pragma unroll
    for (int m = 0; m < BB; m++) {
      float4 x4 = *(const float4*)(xp + (size_t)m * DD + kk);
      acc[m] = fmaf(w4.x, x4.x, fmaf(w4.y, x4.y, fmaf(w4.z, x4.z, fmaf(w4.w, x4.w, acc[m]))));
    }
  }
  float b = valid ? bias[r] : 0.f;
#pragma unroll
  for (int m = 0; m < BB; m++) {
    float v = acc[m];
    v += __shfl_xor(v, 1, 64);
    v += __shfl_xor(v, 2, 64);
    if (c == 0 && valid) Y[(size_t)m * VVOUT + r] = v + b;
  }
}

extern "C" void kernel_launch(void* const* d_in, const int* in_sizes, int n_in,
                              void* d_out, int out_size, void* d_ws, size_t ws_size,
                              hipStream_t stream) {
  const int*   tokens  = (const int*)d_in[0];
  const float* enc     = (const float*)d_in[1];
  const int*   encmask = (const int*)d_in[2];
  const float* emb     = (const float*)d_in[3];
  const float* Wih0    = (const float*)d_in[4];
  const float* bih0    = (const float*)d_in[6];
  const float* bhh0    = (const float*)d_in[7];
  const float* Wih1    = (const float*)d_in[8];
  const float* bih1    = (const float*)d_in[10];
  const float* bhh1    = (const float*)d_in[11];
  const float* preoutW = (const float*)d_in[12];
  const float* preoutb = (const float*)d_in[13];
  const float* outW    = (const float*)d_in[14];
  const float* outb    = (const float*)d_in[15];
  float* out = (float*)d_out;
  float* ws  = (float*)d_ws;

  float* h    = ws;                            // 32*1024
  float* ht   = h + 32 * 1024;                 // 32*1024
  float* part = ht + 32 * 1024;                // 32*32*1032
  float* xcat = part + 32 * 32 * PART_STRIDE;  // 32*2048
  float* opre = xcat + 32 * 2048;              // 32*1024

  // layer 0: X = emb[tokens[m]] (prev_att = 0 -> only first 1024 cols of Wih0)
  gru_fused<true><<<256, 256, 0, stream>>>(emb, tokens, Wih0, 2048, bih0, bhh0, h);
  // layer 1: X = h
  gru_fused<false><<<256, 256, 0, stream>>>(h, tokens, Wih1, 1024, bih1, bhh1, ht);

  attn_partial<<<dim3(BB, NCHUNK), 256, 0, stream>>>(ht, enc, encmask, part);
  attn_reduce<<<BB, 256, 0, stream>>>(part, ht, xcat);

  preout_fused<<<256, 256, 0, stream>>>(xcat, preoutW, preoutb, opre);

  logits_mm<<<(VVOUT + 63) / 64, 256, 0, stream>>>(opre, outW, outb, out);
}